// Round 1
// baseline (517.239 us; speedup 1.0000x reference)
//
#include <hip/hip_runtime.h>

#define D 128            // D_IN == D_OUT == 128
#define NEG_SLOPE 0.01f

// ---------------- utility ----------------
__global__ void zero_i32(int* __restrict__ p, int n) {
    int i = blockIdx.x * blockDim.x + threadIdx.x;
    if (i < n) p[i] = 0;
}

// ---------------- z = h @ W  (16 rows per block, LDS-staged h) ----------------
__global__ __launch_bounds__(256) void gemm_z(const float* __restrict__ h,
                                              const float* __restrict__ W,
                                              float* __restrict__ z, int N) {
    __shared__ float hs[16 * D];       // 8 KB
    const int t = threadIdx.x;
    const int rowBase = blockIdx.x * 16;
    // stage 16 rows of h (coalesced)
    for (int i = t; i < 16 * D; i += 256) {
        int r = rowBase + (i >> 7);
        hs[i] = (r < N) ? h[r * D + (i & 127)] : 0.f;
    }
    __syncthreads();
    const int col = t & 127;
    const int rh  = t >> 7;            // 0..1 -> rows rh*8 .. rh*8+7
    float acc[8] = {0.f, 0.f, 0.f, 0.f, 0.f, 0.f, 0.f, 0.f};
    for (int k = 0; k < D; k += 4) {
        float w0 = W[(k + 0) * D + col];
        float w1 = W[(k + 1) * D + col];
        float w2 = W[(k + 2) * D + col];
        float w3 = W[(k + 3) * D + col];
#pragma unroll
        for (int rr = 0; rr < 8; ++rr) {
            float4 hv = *reinterpret_cast<const float4*>(&hs[(rh * 8 + rr) * D + k]);
            acc[rr] = fmaf(hv.x, w0, acc[rr]);
            acc[rr] = fmaf(hv.y, w1, acc[rr]);
            acc[rr] = fmaf(hv.z, w2, acc[rr]);
            acc[rr] = fmaf(hv.w, w3, acc[rr]);
        }
    }
#pragma unroll
    for (int rr = 0; rr < 8; ++rr) {
        int r = rowBase + rh * 8 + rr;
        if (r < N) z[r * D + col] = acc[rr];
    }
}

// ---------------- s_src / s_dst: one wave per row ----------------
__global__ __launch_bounds__(256) void calc_s(const float* __restrict__ z,
                                              const float* __restrict__ aw,
                                              float* __restrict__ s_src,
                                              float* __restrict__ s_dst, int N) {
    const int lane = threadIdx.x & 63;
    const int row  = blockIdx.x * 4 + (threadIdx.x >> 6);
    if (row >= N) return;
    float z0 = z[row * D + lane];
    float z1 = z[row * D + 64 + lane];
    float ss = z0 * aw[lane]       + z1 * aw[64 + lane];
    float sd = z0 * aw[128 + lane] + z1 * aw[192 + lane];
#pragma unroll
    for (int o = 32; o; o >>= 1) {
        ss += __shfl_xor(ss, o, 64);
        sd += __shfl_xor(sd, o, 64);
    }
    if (lane == 0) { s_src[row] = ss; s_dst[row] = sd; }
}

// ---------------- CSR build ----------------
__global__ void hist_deg(const int* __restrict__ edst, int* __restrict__ deg, int E) {
    int e = blockIdx.x * blockDim.x + threadIdx.x;
    if (e < E) atomicAdd(&deg[edst[e]], 1);
}

__global__ __launch_bounds__(512) void scan1(const int* __restrict__ deg,
                                             int* __restrict__ offs,
                                             int* __restrict__ bsums, int N) {
    __shared__ int sm[512];
    const int t = threadIdx.x;
    const int i = blockIdx.x * 512 + t;
    sm[t] = (i < N) ? deg[i] : 0;
    __syncthreads();
    for (int off = 1; off < 512; off <<= 1) {
        int x = (t >= off) ? sm[t - off] : 0;
        __syncthreads();
        sm[t] += x;
        __syncthreads();
    }
    if (i < N) offs[i + 1] = sm[t];               // inclusive within chunk
    if (t == 511) bsums[blockIdx.x] = sm[511];
}

__global__ __launch_bounds__(256) void scan2(int* __restrict__ bsums, int nb) {
    __shared__ int sm[256];
    const int t = threadIdx.x;
    sm[t] = (t < nb) ? bsums[t] : 0;
    __syncthreads();
    for (int off = 1; off < 256; off <<= 1) {
        int x = (t >= off) ? sm[t - off] : 0;
        __syncthreads();
        sm[t] += x;
        __syncthreads();
    }
    if (t < nb) bsums[t] = (t > 0) ? sm[t - 1] : 0;   // exclusive prefix of chunk sums
}

__global__ __launch_bounds__(512) void scan3(int* __restrict__ offs,
                                             int* __restrict__ cursor,
                                             const int* __restrict__ bsums, int N) {
    const int i = blockIdx.x * 512 + threadIdx.x;
    if (i < N) {
        int v = offs[i + 1] + bsums[blockIdx.x];
        offs[i + 1] = v;
        if (i + 1 < N) cursor[i + 1] = v;
        if (i == 0) { offs[0] = 0; cursor[0] = 0; }
    }
}

__global__ void scatter_adj(const int* __restrict__ esrc, const int* __restrict__ edst,
                            int* __restrict__ cursor, int* __restrict__ adj, int E) {
    int e = blockIdx.x * blockDim.x + threadIdx.x;
    if (e < E) {
        int d = edst[e];
        int pos = atomicAdd(&cursor[d], 1);
        adj[pos] = esrc[e];
    }
}

// ---------------- per-dst-node softmax + weighted sum: one wave per node ----------------
__global__ __launch_bounds__(256) void aggregate(const float* __restrict__ z,
                                                 const float* __restrict__ s_src,
                                                 const float* __restrict__ s_dst,
                                                 const int* __restrict__ offs,
                                                 const int* __restrict__ adj,
                                                 float* __restrict__ out, int N) {
    const int lane = threadIdx.x & 63;
    const int node = blockIdx.x * 4 + (threadIdx.x >> 6);
    if (node >= N) return;
    const int beg = offs[node], end = offs[node + 1];
    const float sd = s_dst[node];

    // pass 1: max over edges (lanes strided)
    float mx = -INFINITY;
    for (int j = beg + lane; j < end; j += 64) {
        float e = s_src[adj[j]] + sd;
        e = (e >= 0.f) ? e : NEG_SLOPE * e;
        mx = fmaxf(mx, e);
    }
#pragma unroll
    for (int o = 32; o; o >>= 1) mx = fmaxf(mx, __shfl_xor(mx, o, 64));

    // pass 2: sum of exp
    float sum = 0.f;
    for (int j = beg + lane; j < end; j += 64) {
        float e = s_src[adj[j]] + sd;
        e = (e >= 0.f) ? e : NEG_SLOPE * e;
        sum += __expf(e - mx);
    }
#pragma unroll
    for (int o = 32; o; o >>= 1) sum += __shfl_xor(sum, o, 64);
    const float inv = (end > beg) ? 1.f / sum : 0.f;

    // pass 3: weighted accumulation, chunks of 64 edges; per-edge weight broadcast
    float a0 = 0.f, a1 = 0.f;
    for (int base = beg; base < end; base += 64) {
        const int cnt = min(64, end - base);
        int s = 0;
        float w = 0.f;
        if (lane < cnt) {
            s = adj[base + lane];
            float e = s_src[s] + sd;
            e = (e >= 0.f) ? e : NEG_SLOPE * e;
            w = __expf(e - mx) * inv;
        }
        for (int j = 0; j < cnt; ++j) {
            float wj = __shfl(w, j, 64);
            int   sj = __shfl(s, j, 64);
            a0 = fmaf(wj, z[sj * D + lane],      a0);
            a1 = fmaf(wj, z[sj * D + 64 + lane], a1);
        }
    }
    out[node * D + lane]      = a0;
    out[node * D + 64 + lane] = a1;
}

// ---------------- launch ----------------
extern "C" void kernel_launch(void* const* d_in, const int* in_sizes, int n_in,
                              void* d_out, int out_size, void* d_ws, size_t ws_size,
                              hipStream_t stream) {
    const float* h    = (const float*)d_in[0];
    const float* W    = (const float*)d_in[1];
    const float* aw   = (const float*)d_in[2];
    const int*   esrc = (const int*)d_in[3];
    const int*   edst = (const int*)d_in[4];
    float* out = (float*)d_out;

    const int N = in_sizes[0] / D;     // 100000
    const int E = in_sizes[3];         // 1600000

    // workspace carve (16B-aligned regions)
    char* p = (char*)d_ws;
    auto carve = [&](size_t bytes) {
        void* r = (void*)p;
        p += (bytes + 255) & ~size_t(255);
        return r;
    };
    float* z      = (float*)carve(size_t(N) * D * sizeof(float));
    float* s_src  = (float*)carve(size_t(N) * sizeof(float));
    float* s_dst  = (float*)carve(size_t(N) * sizeof(float));
    int*   deg    = (int*)carve(size_t(N) * sizeof(int));
    int*   offs   = (int*)carve(size_t(N + 1) * sizeof(int));
    int*   cursor = (int*)carve(size_t(N) * sizeof(int));
    const int NB  = (N + 511) / 512;
    int*   bsums  = (int*)carve(size_t(NB) * sizeof(int));
    int*   adj    = (int*)carve(size_t(E) * sizeof(int));
    (void)ws_size; (void)n_in; (void)out_size;

    // 1) zero degree histogram
    zero_i32<<<(N + 255) / 256, 256, 0, stream>>>(deg, N);
    // 2) z = h @ W
    gemm_z<<<(N + 15) / 16, 256, 0, stream>>>(h, W, z, N);
    // 3) per-node attention scores
    calc_s<<<(N + 3) / 4, 256, 0, stream>>>(z, aw, s_src, s_dst, N);
    // 4) CSR by dst
    hist_deg<<<(E + 255) / 256, 256, 0, stream>>>(edst, deg, E);
    scan1<<<NB, 512, 0, stream>>>(deg, offs, bsums, N);
    scan2<<<1, 256, 0, stream>>>(bsums, NB);
    scan3<<<NB, 512, 0, stream>>>(offs, cursor, bsums, N);
    scatter_adj<<<(E + 255) / 256, 256, 0, stream>>>(esrc, edst, cursor, adj, E);
    // 5) softmax + weighted neighbor sum (one wave per dst node)
    aggregate<<<(N + 3) / 4, 256, 0, stream>>>(z, s_src, s_dst, offs, adj, out, N);
}

// Round 3
// 474.937 us; speedup vs baseline: 1.0891x; 1.0891x over previous
//
#include <hip/hip_runtime.h>

#define D 128            // D_IN == D_OUT == 128
#define NEG_SLOPE 0.01f

// ---------------- utility ----------------
__global__ void zero_i32(int* __restrict__ p, int n) {
    int i = blockIdx.x * blockDim.x + threadIdx.x;
    if (i < n) p[i] = 0;
}

// ---------------- z = h @ W  (32 rows per block; thread = 8 rows x 2 cols) ----
// Per k-group of 4: 8 ds_read_b128 feed 64 FMAs -> VALU-bound,
// vs round-1's 8 reads per 32 FMAs (LDS-pipe-bound).
__global__ __launch_bounds__(256) void gemm_z(const float* __restrict__ h,
                                              const float* __restrict__ W,
                                              float* __restrict__ z, int N) {
    __shared__ float hs[32 * D];       // 16 KB
    const int t = threadIdx.x;
    const int rowBase = blockIdx.x * 32;
    // stage 32 rows of h via float4 (coalesced)
    {
        const float4* __restrict__ hsrc = (const float4*)(h + (size_t)rowBase * D);
        float4* hdst = (float4*)hs;
        for (int i = t; i < 32 * D / 4; i += 256) {
            int r = rowBase + (i >> 5);          // 32 float4 per row
            hdst[i] = (r < N) ? hsrc[i] : make_float4(0.f, 0.f, 0.f, 0.f);
        }
    }
    __syncthreads();
    const int colg  = (t & 63) * 2;              // 2 cols per thread
    const int rbase = (t >> 6) * 8;              // 8 rows per thread (wave-uniform)
    float acc[8][2] = {};
    for (int k = 0; k < D; k += 4) {
        float2 w0 = *(const float2*)&W[(k + 0) * D + colg];
        float2 w1 = *(const float2*)&W[(k + 1) * D + colg];
        float2 w2 = *(const float2*)&W[(k + 2) * D + colg];
        float2 w3 = *(const float2*)&W[(k + 3) * D + colg];
#pragma unroll
        for (int rr = 0; rr < 8; ++rr) {
            // broadcast LDS read (same addr across wave -> conflict-free)
            float4 hv = *(const float4*)&hs[(rbase + rr) * D + k];
            acc[rr][0] = fmaf(hv.x, w0.x, acc[rr][0]);
            acc[rr][1] = fmaf(hv.x, w0.y, acc[rr][1]);
            acc[rr][0] = fmaf(hv.y, w1.x, acc[rr][0]);
            acc[rr][1] = fmaf(hv.y, w1.y, acc[rr][1]);
            acc[rr][0] = fmaf(hv.z, w2.x, acc[rr][0]);
            acc[rr][1] = fmaf(hv.z, w2.y, acc[rr][1]);
            acc[rr][0] = fmaf(hv.w, w3.x, acc[rr][0]);
            acc[rr][1] = fmaf(hv.w, w3.y, acc[rr][1]);
        }
    }
#pragma unroll
    for (int rr = 0; rr < 8; ++rr) {
        int r = rowBase + rbase + rr;
        if (r < N) *(float2*)&z[(size_t)r * D + colg] = make_float2(acc[rr][0], acc[rr][1]);
    }
}

// ---------------- s_src / s_dst: one wave per row ----------------
__global__ __launch_bounds__(256) void calc_s(const float* __restrict__ z,
                                              const float* __restrict__ aw,
                                              float* __restrict__ s_src,
                                              float* __restrict__ s_dst, int N) {
    const int lane = threadIdx.x & 63;
    const int row  = blockIdx.x * 4 + (threadIdx.x >> 6);
    if (row >= N) return;
    float z0 = z[(size_t)row * D + lane];
    float z1 = z[(size_t)row * D + 64 + lane];
    float ss = z0 * aw[lane]       + z1 * aw[64 + lane];
    float sd = z0 * aw[128 + lane] + z1 * aw[192 + lane];
#pragma unroll
    for (int o = 32; o; o >>= 1) {
        ss += __shfl_xor(ss, o, 64);
        sd += __shfl_xor(sd, o, 64);
    }
    if (lane == 0) { s_src[row] = ss; s_dst[row] = sd; }
}

// ---------------- CSR build ----------------
__global__ void hist_deg(const int* __restrict__ edst, int* __restrict__ deg, int E) {
    int e = blockIdx.x * blockDim.x + threadIdx.x;
    if (e < E) atomicAdd(&deg[edst[e]], 1);
}

__global__ __launch_bounds__(512) void scan1(const int* __restrict__ deg,
                                             int* __restrict__ offs,
                                             int* __restrict__ bsums, int N) {
    __shared__ int sm[512];
    const int t = threadIdx.x;
    const int i = blockIdx.x * 512 + t;
    sm[t] = (i < N) ? deg[i] : 0;
    __syncthreads();
    for (int off = 1; off < 512; off <<= 1) {
        int x = (t >= off) ? sm[t - off] : 0;
        __syncthreads();
        sm[t] += x;
        __syncthreads();
    }
    if (i < N) offs[i + 1] = sm[t];               // inclusive within chunk
    if (t == 511) bsums[blockIdx.x] = sm[511];
}

__global__ __launch_bounds__(256) void scan2(int* __restrict__ bsums, int nb) {
    __shared__ int sm[256];
    const int t = threadIdx.x;
    sm[t] = (t < nb) ? bsums[t] : 0;
    __syncthreads();
    for (int off = 1; off < 256; off <<= 1) {
        int x = (t >= off) ? sm[t - off] : 0;
        __syncthreads();
        sm[t] += x;
        __syncthreads();
    }
    if (t < nb) bsums[t] = (t > 0) ? sm[t - 1] : 0;   // exclusive prefix of chunk sums
}

__global__ __launch_bounds__(512) void scan3(int* __restrict__ offs,
                                             int* __restrict__ cursor,
                                             const int* __restrict__ bsums, int N) {
    const int i = blockIdx.x * 512 + threadIdx.x;
    if (i < N) {
        int v = offs[i + 1] + bsums[blockIdx.x];
        offs[i + 1] = v;
        if (i + 1 < N) cursor[i + 1] = v;
        if (i == 0) { offs[0] = 0; cursor[0] = 0; }
    }
}

__global__ void scatter_adj(const int* __restrict__ esrc, const int* __restrict__ edst,
                            int* __restrict__ cursor, int* __restrict__ adj, int E) {
    int e = blockIdx.x * blockDim.x + threadIdx.x;
    if (e < E) {
        int d = edst[e];
        int pos = atomicAdd(&cursor[d], 1);
        adj[pos] = esrc[e];
    }
}

// ---------------- per-dst-node softmax + weighted sum: one wave per node ------
// CORRECTNESS RULE (round-2 bug): every __shfl must execute with ALL 64 lanes
// active. Loop bounds are wave-uniform; per-lane edge validity is handled by
// predicating the shfl'd VALUE (v_cndmask), never the control flow. Lanes
// >= cnt carry w=0, s=0 so stray reads are value-safe (weight-0 * z row 0).
__global__ __launch_bounds__(256) void aggregate(const float* __restrict__ z,
                                                 const float* __restrict__ s_src,
                                                 const float* __restrict__ s_dst,
                                                 const int* __restrict__ offs,
                                                 const int* __restrict__ adj,
                                                 float* __restrict__ out, int N) {
    const int lane = threadIdx.x & 63;
    const int half = lane >> 5;
    const int l32  = lane & 31;
    const int node = blockIdx.x * 4 + (threadIdx.x >> 6);
    if (node >= N) return;
    const int beg = offs[node];
    const int cnt = offs[node + 1] - beg;
    const float sd = s_dst[node];

    float4 accA = make_float4(0.f, 0.f, 0.f, 0.f);
    float4 accB = make_float4(0.f, 0.f, 0.f, 0.f);

    if (cnt <= 64) {
        // ---- fast path (all nodes at Poisson(16) degree): one gather per edge
        int s = 0; float e = -INFINITY;
        if (lane < cnt) {
            s = adj[beg + lane];
            float t = s_src[s] + sd;
            e = (t >= 0.f) ? t : NEG_SLOPE * t;
        }
        float mx = e;
#pragma unroll
        for (int o = 32; o; o >>= 1) mx = fmaxf(mx, __shfl_xor(mx, o, 64));
        float ex = (lane < cnt) ? __expf(e - mx) : 0.f;
        float sum = ex;
#pragma unroll
        for (int o = 32; o; o >>= 1) sum += __shfl_xor(sum, o, 64);
        const float inv = (cnt > 0) ? 1.f / sum : 0.f;
        const float w = ex * inv;       // 0 for lanes >= cnt

        // uniform trip count; half0 takes even edges, half1 odd; 4 edges/iter.
        for (int jj = 0; jj < cnt; jj += 4) {
            const int ja = jj + half;          // <= 61
            const int jb = ja + 2;             // <= 63
            float wa = __shfl(w, ja, 64); int sa = __shfl(s, ja, 64);
            float wb = __shfl(w, jb, 64); int sb = __shfl(s, jb, 64);
            wa = (ja < cnt) ? wa : 0.f;        // value predication, exec-safe
            wb = (jb < cnt) ? wb : 0.f;
            float4 za = *(const float4*)&z[(size_t)sa * D + l32 * 4];
            float4 zb = *(const float4*)&z[(size_t)sb * D + l32 * 4];
            accA.x = fmaf(wa, za.x, accA.x); accA.y = fmaf(wa, za.y, accA.y);
            accA.z = fmaf(wa, za.z, accA.z); accA.w = fmaf(wa, za.w, accA.w);
            accB.x = fmaf(wb, zb.x, accB.x); accB.y = fmaf(wb, zb.y, accB.y);
            accB.z = fmaf(wb, zb.z, accB.z); accB.w = fmaf(wb, zb.w, accB.w);
        }
    } else {
        // ---- rare general path (cnt > 64): 3-pass chunked, same shfl rule
        float mx = -INFINITY;
        for (int j = lane; j < cnt; j += 64) {
            float t = s_src[adj[beg + j]] + sd;
            t = (t >= 0.f) ? t : NEG_SLOPE * t;
            mx = fmaxf(mx, t);
        }
#pragma unroll
        for (int o = 32; o; o >>= 1) mx = fmaxf(mx, __shfl_xor(mx, o, 64));
        float sum = 0.f;
        for (int j = lane; j < cnt; j += 64) {
            float t = s_src[adj[beg + j]] + sd;
            t = (t >= 0.f) ? t : NEG_SLOPE * t;
            sum += __expf(t - mx);
        }
#pragma unroll
        for (int o = 32; o; o >>= 1) sum += __shfl_xor(sum, o, 64);
        const float inv = 1.f / sum;
        for (int base = 0; base < cnt; base += 64) {
            const int cc = min(64, cnt - base);
            int s = 0; float w = 0.f;
            if (lane < cc) {
                s = adj[beg + base + lane];
                float t = s_src[s] + sd;
                t = (t >= 0.f) ? t : NEG_SLOPE * t;
                w = __expf(t - mx) * inv;
            }
            for (int jj = 0; jj < cc; jj += 4) {
                const int ja = jj + half;
                const int jb = ja + 2;
                float wa = __shfl(w, ja, 64); int sa = __shfl(s, ja, 64);
                float wb = __shfl(w, jb, 64); int sb = __shfl(s, jb, 64);
                wa = (ja < cc) ? wa : 0.f;
                wb = (jb < cc) ? wb : 0.f;
                float4 za = *(const float4*)&z[(size_t)sa * D + l32 * 4];
                float4 zb = *(const float4*)&z[(size_t)sb * D + l32 * 4];
                accA.x = fmaf(wa, za.x, accA.x); accA.y = fmaf(wa, za.y, accA.y);
                accA.z = fmaf(wa, za.z, accA.z); accA.w = fmaf(wa, za.w, accA.w);
                accB.x = fmaf(wb, zb.x, accB.x); accB.y = fmaf(wb, zb.y, accB.y);
                accB.z = fmaf(wb, zb.z, accB.z); accB.w = fmaf(wb, zb.w, accB.w);
            }
        }
    }

    // merge two accumulators, then the two halves (xor-32, full exec), write
    accA.x += accB.x; accA.y += accB.y; accA.z += accB.z; accA.w += accB.w;
    accA.x += __shfl_xor(accA.x, 32, 64);
    accA.y += __shfl_xor(accA.y, 32, 64);
    accA.z += __shfl_xor(accA.z, 32, 64);
    accA.w += __shfl_xor(accA.w, 32, 64);
    if (half == 0)
        *(float4*)&out[(size_t)node * D + l32 * 4] = accA;
}

// ---------------- launch ----------------
extern "C" void kernel_launch(void* const* d_in, const int* in_sizes, int n_in,
                              void* d_out, int out_size, void* d_ws, size_t ws_size,
                              hipStream_t stream) {
    const float* h    = (const float*)d_in[0];
    const float* W    = (const float*)d_in[1];
    const float* aw   = (const float*)d_in[2];
    const int*   esrc = (const int*)d_in[3];
    const int*   edst = (const int*)d_in[4];
    float* out = (float*)d_out;

    const int N = in_sizes[0] / D;     // 100000
    const int E = in_sizes[3];         // 1600000

    // workspace carve (256B-aligned regions)
    char* p = (char*)d_ws;
    auto carve = [&](size_t bytes) {
        void* r = (void*)p;
        p += (bytes + 255) & ~size_t(255);
        return r;
    };
    float* z      = (float*)carve(size_t(N) * D * sizeof(float));
    float* s_src  = (float*)carve(size_t(N) * sizeof(float));
    float* s_dst  = (float*)carve(size_t(N) * sizeof(float));
    int*   deg    = (int*)carve(size_t(N) * sizeof(int));
    int*   offs   = (int*)carve(size_t(N + 1) * sizeof(int));
    int*   cursor = (int*)carve(size_t(N) * sizeof(int));
    const int NB  = (N + 511) / 512;
    int*   bsums  = (int*)carve(size_t(NB) * sizeof(int));
    int*   adj    = (int*)carve(size_t(E) * sizeof(int));
    (void)ws_size; (void)n_in; (void)out_size;

    zero_i32<<<(N + 255) / 256, 256, 0, stream>>>(deg, N);
    gemm_z<<<(N + 31) / 32, 256, 0, stream>>>(h, W, z, N);
    calc_s<<<(N + 3) / 4, 256, 0, stream>>>(z, aw, s_src, s_dst, N);
    hist_deg<<<(E + 255) / 256, 256, 0, stream>>>(edst, deg, E);
    scan1<<<NB, 512, 0, stream>>>(deg, offs, bsums, N);
    scan2<<<1, 256, 0, stream>>>(bsums, NB);
    scan3<<<NB, 512, 0, stream>>>(offs, cursor, bsums, N);
    scatter_adj<<<(E + 255) / 256, 256, 0, stream>>>(esrc, edst, cursor, adj, E);
    aggregate<<<(N + 3) / 4, 256, 0, stream>>>(z, s_src, s_dst, offs, adj, out, N);
}

// Round 4
// 458.357 us; speedup vs baseline: 1.1285x; 1.0362x over previous
//
#include <hip/hip_runtime.h>

#define D 128            // D_IN == D_OUT == 128
#define NEG_SLOPE 0.01f
#define BSHIFT 7         // 128 dst values per coarse bucket
#define B1 1024          // max coarse buckets (N <= 131072)
#define NG 8             // writer groups (~XCDs) per bucket

// ---------------- utility ----------------
__global__ void zero_i32(int* __restrict__ p, int n) {
    int i = blockIdx.x * blockDim.x + threadIdx.x;
    if (i < n) p[i] = 0;
}

// ---- z = h @ W (32 rows/block; thread = 8 rows x 2 cols) + fused attn scores
// Epilogue computes s_src/s_dst from the accumulators (no z re-read).
__global__ __launch_bounds__(256) void gemm_zs(const float* __restrict__ h,
                                               const float* __restrict__ W,
                                               const float* __restrict__ aw,
                                               float* __restrict__ z,
                                               float* __restrict__ s_src,
                                               float* __restrict__ s_dst, int N) {
    __shared__ float hs[32 * D];       // 16 KB
    const int t = threadIdx.x;
    const int rowBase = blockIdx.x * 32;
    {
        const float4* __restrict__ hsrc = (const float4*)(h + (size_t)rowBase * D);
        float4* hdst = (float4*)hs;
        for (int i = t; i < 32 * D / 4; i += 256) {
            int r = rowBase + (i >> 5);
            hdst[i] = (r < N) ? hsrc[i] : make_float4(0.f, 0.f, 0.f, 0.f);
        }
    }
    __syncthreads();
    const int lane  = t & 63;
    const int colg  = lane * 2;                  // 2 cols per thread
    const int rbase = (t >> 6) * 8;              // 8 rows per thread (wave-uniform)
    float acc[8][2] = {};
    for (int k = 0; k < D; k += 4) {
        float2 w0 = *(const float2*)&W[(k + 0) * D + colg];
        float2 w1 = *(const float2*)&W[(k + 1) * D + colg];
        float2 w2 = *(const float2*)&W[(k + 2) * D + colg];
        float2 w3 = *(const float2*)&W[(k + 3) * D + colg];
#pragma unroll
        for (int rr = 0; rr < 8; ++rr) {
            float4 hv = *(const float4*)&hs[(rbase + rr) * D + k];   // wave-broadcast
            acc[rr][0] = fmaf(hv.x, w0.x, acc[rr][0]);
            acc[rr][1] = fmaf(hv.x, w0.y, acc[rr][1]);
            acc[rr][0] = fmaf(hv.y, w1.x, acc[rr][0]);
            acc[rr][1] = fmaf(hv.y, w1.y, acc[rr][1]);
            acc[rr][0] = fmaf(hv.z, w2.x, acc[rr][0]);
            acc[rr][1] = fmaf(hv.z, w2.y, acc[rr][1]);
            acc[rr][0] = fmaf(hv.w, w3.x, acc[rr][0]);
            acc[rr][1] = fmaf(hv.w, w3.y, acc[rr][1]);
        }
    }
    // write z
#pragma unroll
    for (int rr = 0; rr < 8; ++rr) {
        int r = rowBase + rbase + rr;
        if (r < N) *(float2*)&z[(size_t)r * D + colg] = make_float2(acc[rr][0], acc[rr][1]);
    }
    // fused attention scores: per-row dot with aw[:128] / aw[128:]
    const float a0s = aw[colg],       a1s = aw[colg + 1];
    const float a0d = aw[128 + colg], a1d = aw[129 + colg];
#pragma unroll
    for (int rr = 0; rr < 8; ++rr) {
        float ss = fmaf(acc[rr][1], a1s, acc[rr][0] * a0s);
        float sd = fmaf(acc[rr][1], a1d, acc[rr][0] * a0d);
#pragma unroll
        for (int o = 32; o; o >>= 1) {
            ss += __shfl_xor(ss, o, 64);
            sd += __shfl_xor(sd, o, 64);
        }
        int r = rowBase + rbase + rr;
        if (lane == 0 && r < N) { s_src[r] = ss; s_dst[r] = sd; }
    }
}

// ---------------- CSR build: two-level counting sort ----------------
// K2: count per (bucket, writer-group). Same g mapping as the scatter pass.
__global__ __launch_bounds__(256) void coarse_count(const int* __restrict__ edst,
                                                    int* __restrict__ ccnt, int E) {
    int e = blockIdx.x * 256 + threadIdx.x;
    if (e < E) {
        int bkt = edst[e] >> BSHIFT;
        atomicAdd(&ccnt[bkt * NG + (blockIdx.x & (NG - 1))], 1);
    }
}

// K3: single block. Scan 8192 counters -> bucket starts + group cursors.
__global__ __launch_bounds__(1024) void bucket_scan(const int* __restrict__ ccnt,
                                                    int* __restrict__ gs,
                                                    int* __restrict__ gcur,
                                                    int* __restrict__ bstart,
                                                    int* __restrict__ offs,
                                                    int E, int N) {
    __shared__ int sm[B1];
    const int t = threadIdx.x;
    int c[NG]; int tot = 0;
#pragma unroll
    for (int g = 0; g < NG; ++g) { c[g] = ccnt[t * NG + g]; tot += c[g]; }
    sm[t] = tot;
    __syncthreads();
    for (int off = 1; off < B1; off <<= 1) {
        int v = (t >= off) ? sm[t - off] : 0;
        __syncthreads();
        sm[t] += v;
        __syncthreads();
    }
    int excl = sm[t] - tot;
    bstart[t] = excl;
    int run = excl;
#pragma unroll
    for (int g = 0; g < NG; ++g) {
        gs[t * NG + g] = run;
        gcur[t * NG + g] = run;
        run += c[g];
    }
    if (t == 0) offs[N] = E;
}

// K4: scatter (src,dst) into per-(bucket,group) dense regions.
__global__ __launch_bounds__(256) void coarse_scatter(const int* __restrict__ esrc,
                                                      const int* __restrict__ edst,
                                                      int* __restrict__ gcur,
                                                      int2* __restrict__ pairs, int E) {
    int e = blockIdx.x * 256 + threadIdx.x;
    if (e < E) {
        int d = edst[e];
        int bkt = d >> BSHIFT;
        int pos = atomicAdd(&gcur[bkt * NG + (blockIdx.x & (NG - 1))], 1);
        pairs[pos] = make_int2(esrc[e], d);
    }
}

// K5: one block per bucket. LDS histogram+scan over 128 dsts -> offs + adj.
// Replaces hist_deg + 3 scan kernels + global scatter; adj segment write is
// dense (8KB, single CU).
__global__ __launch_bounds__(256) void fine_build(const int2* __restrict__ pairs,
                                                  const int* __restrict__ gs,
                                                  const int* __restrict__ gcur,
                                                  const int* __restrict__ bstart,
                                                  int* __restrict__ offs,
                                                  int* __restrict__ adj, int N) {
    __shared__ int cnt[128], sc[128], cur[128];
    const int b = blockIdx.x;
    const int base = b << BSHIFT;
    const int nd = min(128, N - base);
    const int t = threadIdx.x;
    if (t < 128) { cnt[t] = 0; cur[t] = 0; }
    __syncthreads();
    // count
#pragma unroll
    for (int g = 0; g < NG; ++g) {
        const int s0 = gs[b * NG + g], e0 = gcur[b * NG + g];
        for (int i = s0 + t; i < e0; i += 256)
            atomicAdd(&cnt[pairs[i].y - base], 1);
    }
    __syncthreads();
    // inclusive scan of cnt into sc (128 wide, full-block barriers)
    if (t < 128) sc[t] = cnt[t];
    __syncthreads();
    for (int off = 1; off < 128; off <<= 1) {
        int v = (t < 128 && t >= off) ? sc[t - off] : 0;
        __syncthreads();
        if (t < 128) sc[t] += v;
        __syncthreads();
    }
    const int bs = bstart[b];
    if (t < nd) offs[base + t] = bs + sc[t] - cnt[t];     // exclusive
    __syncthreads();
    // scatter into the bucket's contiguous adj segment
#pragma unroll
    for (int g = 0; g < NG; ++g) {
        const int s0 = gs[b * NG + g], e0 = gcur[b * NG + g];
        for (int i = s0 + t; i < e0; i += 256) {
            int2 p = pairs[i];
            int d = p.y - base;
            int pos = bs + (sc[d] - cnt[d]) + atomicAdd(&cur[d], 1);
            adj[pos] = p.x;
        }
    }
}

// ---------------- per-dst-node softmax + weighted sum: one wave per node ------
// CORRECTNESS RULE: every __shfl executes with ALL 64 lanes active; loop
// bounds wave-uniform; validity handled by predicating shfl'd VALUES.
__global__ __launch_bounds__(256) void aggregate(const float* __restrict__ z,
                                                 const float* __restrict__ s_src,
                                                 const float* __restrict__ s_dst,
                                                 const int* __restrict__ offs,
                                                 const int* __restrict__ adj,
                                                 float* __restrict__ out, int N) {
    const int lane = threadIdx.x & 63;
    const int half = lane >> 5;
    const int l32  = lane & 31;
    const int node = blockIdx.x * 4 + (threadIdx.x >> 6);
    if (node >= N) return;
    const int beg = offs[node];
    const int cnt = offs[node + 1] - beg;
    const float sd = s_dst[node];

    float4 accA = make_float4(0.f, 0.f, 0.f, 0.f);
    float4 accB = make_float4(0.f, 0.f, 0.f, 0.f);

    if (cnt <= 64) {
        int s = 0; float e = -INFINITY;
        if (lane < cnt) {
            s = adj[beg + lane];
            float t = s_src[s] + sd;
            e = (t >= 0.f) ? t : NEG_SLOPE * t;
        }
        float mx = e;
#pragma unroll
        for (int o = 32; o; o >>= 1) mx = fmaxf(mx, __shfl_xor(mx, o, 64));
        float ex = (lane < cnt) ? __expf(e - mx) : 0.f;
        float sum = ex;
#pragma unroll
        for (int o = 32; o; o >>= 1) sum += __shfl_xor(sum, o, 64);
        const float inv = (cnt > 0) ? 1.f / sum : 0.f;
        const float w = ex * inv;       // 0 for lanes >= cnt

        for (int jj = 0; jj < cnt; jj += 4) {
            const int ja = jj + half;
            const int jb = ja + 2;
            float wa = __shfl(w, ja, 64); int sa = __shfl(s, ja, 64);
            float wb = __shfl(w, jb, 64); int sb = __shfl(s, jb, 64);
            wa = (ja < cnt) ? wa : 0.f;
            wb = (jb < cnt) ? wb : 0.f;
            float4 za = *(const float4*)&z[(size_t)sa * D + l32 * 4];
            float4 zb = *(const float4*)&z[(size_t)sb * D + l32 * 4];
            accA.x = fmaf(wa, za.x, accA.x); accA.y = fmaf(wa, za.y, accA.y);
            accA.z = fmaf(wa, za.z, accA.z); accA.w = fmaf(wa, za.w, accA.w);
            accB.x = fmaf(wb, zb.x, accB.x); accB.y = fmaf(wb, zb.y, accB.y);
            accB.z = fmaf(wb, zb.z, accB.z); accB.w = fmaf(wb, zb.w, accB.w);
        }
    } else {
        float mx = -INFINITY;
        for (int j = lane; j < cnt; j += 64) {
            float t = s_src[adj[beg + j]] + sd;
            t = (t >= 0.f) ? t : NEG_SLOPE * t;
            mx = fmaxf(mx, t);
        }
#pragma unroll
        for (int o = 32; o; o >>= 1) mx = fmaxf(mx, __shfl_xor(mx, o, 64));
        float sum = 0.f;
        for (int j = lane; j < cnt; j += 64) {
            float t = s_src[adj[beg + j]] + sd;
            t = (t >= 0.f) ? t : NEG_SLOPE * t;
            sum += __expf(t - mx);
        }
#pragma unroll
        for (int o = 32; o; o >>= 1) sum += __shfl_xor(sum, o, 64);
        const float inv = 1.f / sum;
        for (int base2 = 0; base2 < cnt; base2 += 64) {
            const int cc = min(64, cnt - base2);
            int s = 0; float w = 0.f;
            if (lane < cc) {
                s = adj[beg + base2 + lane];
                float t = s_src[s] + sd;
                t = (t >= 0.f) ? t : NEG_SLOPE * t;
                w = __expf(t - mx) * inv;
            }
            for (int jj = 0; jj < cc; jj += 4) {
                const int ja = jj + half;
                const int jb = ja + 2;
                float wa = __shfl(w, ja, 64); int sa = __shfl(s, ja, 64);
                float wb = __shfl(w, jb, 64); int sb = __shfl(s, jb, 64);
                wa = (ja < cc) ? wa : 0.f;
                wb = (jb < cc) ? wb : 0.f;
                float4 za = *(const float4*)&z[(size_t)sa * D + l32 * 4];
                float4 zb = *(const float4*)&z[(size_t)sb * D + l32 * 4];
                accA.x = fmaf(wa, za.x, accA.x); accA.y = fmaf(wa, za.y, accA.y);
                accA.z = fmaf(wa, za.z, accA.z); accA.w = fmaf(wa, za.w, accA.w);
                accB.x = fmaf(wb, zb.x, accB.x); accB.y = fmaf(wb, zb.y, accB.y);
                accB.z = fmaf(wb, zb.z, accB.z); accB.w = fmaf(wb, zb.w, accB.w);
            }
        }
    }

    accA.x += accB.x; accA.y += accB.y; accA.z += accB.z; accA.w += accB.w;
    accA.x += __shfl_xor(accA.x, 32, 64);
    accA.y += __shfl_xor(accA.y, 32, 64);
    accA.z += __shfl_xor(accA.z, 32, 64);
    accA.w += __shfl_xor(accA.w, 32, 64);
    if (half == 0)
        *(float4*)&out[(size_t)node * D + l32 * 4] = accA;
}

// ---------------- launch ----------------
extern "C" void kernel_launch(void* const* d_in, const int* in_sizes, int n_in,
                              void* d_out, int out_size, void* d_ws, size_t ws_size,
                              hipStream_t stream) {
    const float* h    = (const float*)d_in[0];
    const float* W    = (const float*)d_in[1];
    const float* aw   = (const float*)d_in[2];
    const int*   esrc = (const int*)d_in[3];
    const int*   edst = (const int*)d_in[4];
    float* out = (float*)d_out;

    const int N = in_sizes[0] / D;     // 100000
    const int E = in_sizes[3];         // 1600000
    const int NB1 = (N + 127) >> BSHIFT;   // used buckets

    char* p = (char*)d_ws;
    auto carve = [&](size_t bytes) {
        void* r = (void*)p;
        p += (bytes + 255) & ~size_t(255);
        return r;
    };
    float* z      = (float*)carve(size_t(N) * D * sizeof(float));
    float* s_src  = (float*)carve(size_t(N) * sizeof(float));
    float* s_dst  = (float*)carve(size_t(N) * sizeof(float));
    int*   offs   = (int*)carve(size_t(N + 1) * sizeof(int));
    int*   adj    = (int*)carve(size_t(E) * sizeof(int));
    int2*  pairs  = (int2*)carve(size_t(E) * sizeof(int2));
    int*   ccnt   = (int*)carve(size_t(B1 * NG) * sizeof(int));
    int*   gs     = (int*)carve(size_t(B1 * NG) * sizeof(int));
    int*   gcur   = (int*)carve(size_t(B1 * NG) * sizeof(int));
    int*   bstart = (int*)carve(size_t(B1) * sizeof(int));
    (void)ws_size; (void)n_in; (void)out_size;

    zero_i32<<<(B1 * NG + 255) / 256, 256, 0, stream>>>(ccnt, B1 * NG);
    gemm_zs<<<(N + 31) / 32, 256, 0, stream>>>(h, W, aw, z, s_src, s_dst, N);
    coarse_count<<<(E + 255) / 256, 256, 0, stream>>>(edst, ccnt, E);
    bucket_scan<<<1, B1, 0, stream>>>(ccnt, gs, gcur, bstart, offs, E, N);
    coarse_scatter<<<(E + 255) / 256, 256, 0, stream>>>(esrc, edst, gcur, pairs, E);
    fine_build<<<NB1, 256, 0, stream>>>(pairs, gs, gcur, bstart, offs, adj, N);
    aggregate<<<(N + 3) / 4, 256, 0, stream>>>(z, s_src, s_dst, offs, adj, out, N);
}

// Round 5
// 428.845 us; speedup vs baseline: 1.2061x; 1.0688x over previous
//
#include <hip/hip_runtime.h>

#define D 128            // D_IN == D_OUT == 128
#define NEG_SLOPE 0.01f
#define BSHIFT 7         // 128 dst values per coarse bucket
#define B1 1024          // max coarse buckets (N <= 131072)
#define NG 8             // writer groups (~XCDs) per bucket

// bf16 helpers (z is stored bf16: halves aggregate's gather traffic; scores
// are computed from fp32 accumulators so softmax weights are unaffected)
__device__ __forceinline__ unsigned f2bf_rne(float x) {
    unsigned u = __float_as_uint(x);
    return (u + 0x7fffu + ((u >> 16) & 1u)) >> 16;
}
#define BF_LO(u) __uint_as_float((u) << 16)
#define BF_HI(u) __uint_as_float((u) & 0xffff0000u)

// ---------------- utility ----------------
__global__ void zero_i32(int* __restrict__ p, int n) {
    int i = blockIdx.x * blockDim.x + threadIdx.x;
    if (i < n) p[i] = 0;
}

// ---- z = h @ W (32 rows/block; thread = 8 rows x 2 cols) + fused attn scores
// W staged in LDS once per block (was: every wave re-streamed 64KB of W from
// L2 each k-loop => ~1.6GB L2 traffic). LDS 16+64=80KB -> 2 blocks/CU.
__global__ __launch_bounds__(256) void gemm_zs(const float* __restrict__ h,
                                               const float* __restrict__ W,
                                               const float* __restrict__ aw,
                                               unsigned short* __restrict__ z,
                                               float* __restrict__ s_src,
                                               float* __restrict__ s_dst, int N) {
    __shared__ float hs[32 * D];       // 16 KB
    __shared__ float ws[D * D];        // 64 KB
    const int t = threadIdx.x;
    const int rowBase = blockIdx.x * 32;
    {   // stage W (coalesced float4), once per block
        const float4* __restrict__ wsrc = (const float4*)W;
        float4* wdst = (float4*)ws;
        for (int i = t; i < D * D / 4; i += 256) wdst[i] = wsrc[i];
    }
    {   // stage h rows
        const float4* __restrict__ hsrc = (const float4*)(h + (size_t)rowBase * D);
        float4* hdst = (float4*)hs;
        for (int i = t; i < 32 * D / 4; i += 256) {
            int r = rowBase + (i >> 5);
            hdst[i] = (r < N) ? hsrc[i] : make_float4(0.f, 0.f, 0.f, 0.f);
        }
    }
    __syncthreads();
    const int lane  = t & 63;
    const int colg  = lane * 2;                  // 2 cols per thread
    const int rbase = (t >> 6) * 8;              // 8 rows per thread (wave-uniform)
    float acc[8][2] = {};
    for (int k = 0; k < D; k += 4) {
        float2 w0 = *(const float2*)&ws[(k + 0) * D + colg];   // 2-way bank alias: free
        float2 w1 = *(const float2*)&ws[(k + 1) * D + colg];
        float2 w2 = *(const float2*)&ws[(k + 2) * D + colg];
        float2 w3 = *(const float2*)&ws[(k + 3) * D + colg];
#pragma unroll
        for (int rr = 0; rr < 8; ++rr) {
            float4 hv = *(const float4*)&hs[(rbase + rr) * D + k];   // wave-broadcast
            acc[rr][0] = fmaf(hv.x, w0.x, acc[rr][0]);
            acc[rr][1] = fmaf(hv.x, w0.y, acc[rr][1]);
            acc[rr][0] = fmaf(hv.y, w1.x, acc[rr][0]);
            acc[rr][1] = fmaf(hv.y, w1.y, acc[rr][1]);
            acc[rr][0] = fmaf(hv.z, w2.x, acc[rr][0]);
            acc[rr][1] = fmaf(hv.z, w2.y, acc[rr][1]);
            acc[rr][0] = fmaf(hv.w, w3.x, acc[rr][0]);
            acc[rr][1] = fmaf(hv.w, w3.y, acc[rr][1]);
        }
    }
    // write z as packed bf16 (coalesced dword stores, colg is even)
#pragma unroll
    for (int rr = 0; rr < 8; ++rr) {
        int r = rowBase + rbase + rr;
        if (r < N) {
            unsigned pz = f2bf_rne(acc[rr][0]) | (f2bf_rne(acc[rr][1]) << 16);
            *(unsigned*)&z[(size_t)r * D + colg] = pz;
        }
    }
    // fused attention scores from fp32 accumulators
    const float a0s = aw[colg],       a1s = aw[colg + 1];
    const float a0d = aw[128 + colg], a1d = aw[129 + colg];
#pragma unroll
    for (int rr = 0; rr < 8; ++rr) {
        float ss = fmaf(acc[rr][1], a1s, acc[rr][0] * a0s);
        float sd = fmaf(acc[rr][1], a1d, acc[rr][0] * a0d);
#pragma unroll
        for (int o = 32; o; o >>= 1) {
            ss += __shfl_xor(ss, o, 64);
            sd += __shfl_xor(sd, o, 64);
        }
        int r = rowBase + rbase + rr;
        if (lane == 0 && r < N) { s_src[r] = ss; s_dst[r] = sd; }
    }
}

// ---------------- CSR build: two-level counting sort ----------------
__global__ __launch_bounds__(256) void coarse_count(const int* __restrict__ edst,
                                                    int* __restrict__ ccnt, int E) {
    int e = blockIdx.x * 256 + threadIdx.x;
    if (e < E) {
        int bkt = edst[e] >> BSHIFT;
        atomicAdd(&ccnt[bkt * NG + (blockIdx.x & (NG - 1))], 1);
    }
}

__global__ __launch_bounds__(1024) void bucket_scan(const int* __restrict__ ccnt,
                                                    int* __restrict__ gs,
                                                    int* __restrict__ gcur,
                                                    int* __restrict__ bstart,
                                                    int* __restrict__ offs,
                                                    int E, int N) {
    __shared__ int sm[B1];
    const int t = threadIdx.x;
    int c[NG]; int tot = 0;
#pragma unroll
    for (int g = 0; g < NG; ++g) { c[g] = ccnt[t * NG + g]; tot += c[g]; }
    sm[t] = tot;
    __syncthreads();
    for (int off = 1; off < B1; off <<= 1) {
        int v = (t >= off) ? sm[t - off] : 0;
        __syncthreads();
        sm[t] += v;
        __syncthreads();
    }
    int excl = sm[t] - tot;
    bstart[t] = excl;
    int run = excl;
#pragma unroll
    for (int g = 0; g < NG; ++g) {
        gs[t * NG + g] = run;
        gcur[t * NG + g] = run;
        run += c[g];
    }
    if (t == 0) offs[N] = E;
}

// scatter packed (src<<7 | dst&127) into per-(bucket,group) dense regions.
// Valid since N <= 131072 = 2^17 and 17+7 = 24 bits.
__global__ __launch_bounds__(256) void coarse_scatter(const int* __restrict__ esrc,
                                                      const int* __restrict__ edst,
                                                      int* __restrict__ gcur,
                                                      int* __restrict__ pairs, int E) {
    int e = blockIdx.x * 256 + threadIdx.x;
    if (e < E) {
        int d = edst[e];
        int bkt = d >> BSHIFT;
        int pos = atomicAdd(&gcur[bkt * NG + (blockIdx.x & (NG - 1))], 1);
        pairs[pos] = (esrc[e] << BSHIFT) | (d & 127);
    }
}

// one block per bucket: LDS histogram+scan over 128 dsts -> offs + adj.
__global__ __launch_bounds__(256) void fine_build(const int* __restrict__ pairs,
                                                  const int* __restrict__ gs,
                                                  const int* __restrict__ gcur,
                                                  const int* __restrict__ bstart,
                                                  int* __restrict__ offs,
                                                  int* __restrict__ adj, int N) {
    __shared__ int cnt[128], sc[128], cur[128];
    const int b = blockIdx.x;
    const int base = b << BSHIFT;
    const int nd = min(128, N - base);
    const int t = threadIdx.x;
    if (t < 128) { cnt[t] = 0; cur[t] = 0; }
    __syncthreads();
#pragma unroll
    for (int g = 0; g < NG; ++g) {
        const int s0 = gs[b * NG + g], e0 = gcur[b * NG + g];
        for (int i = s0 + t; i < e0; i += 256)
            atomicAdd(&cnt[pairs[i] & 127], 1);
    }
    __syncthreads();
    if (t < 128) sc[t] = cnt[t];
    __syncthreads();
    for (int off = 1; off < 128; off <<= 1) {
        int v = (t < 128 && t >= off) ? sc[t - off] : 0;
        __syncthreads();
        if (t < 128) sc[t] += v;
        __syncthreads();
    }
    const int bs = bstart[b];
    if (t < nd) offs[base + t] = bs + sc[t] - cnt[t];     // exclusive
    __syncthreads();
#pragma unroll
    for (int g = 0; g < NG; ++g) {
        const int s0 = gs[b * NG + g], e0 = gcur[b * NG + g];
        for (int i = s0 + t; i < e0; i += 256) {
            int pk = pairs[i];
            int d = pk & 127;
            int pos = bs + (sc[d] - cnt[d]) + atomicAdd(&cur[d], 1);
            adj[pos] = pk >> BSHIFT;
        }
    }
}

// ---------------- per-dst-node softmax + weighted sum: one wave per node ------
// z rows are bf16 (256B): each 16-lane QUAD covers one row (16B/lane uint4),
// 4 edges/iter, x2 unroll = 8 rows in flight. CORRECTNESS RULE: every __shfl
// executes with ALL 64 lanes active; loop bounds wave-uniform; validity via
// value predication of the shfl'd weight.
__global__ __launch_bounds__(256) void aggregate(const unsigned short* __restrict__ z,
                                                 const float* __restrict__ s_src,
                                                 const float* __restrict__ s_dst,
                                                 const int* __restrict__ offs,
                                                 const int* __restrict__ adj,
                                                 float* __restrict__ out, int N) {
    const int lane = threadIdx.x & 63;
    const int q    = lane >> 4;          // quad 0..3
    const int l16  = lane & 15;
    const int node = blockIdx.x * 4 + (threadIdx.x >> 6);
    if (node >= N) return;
    const int beg = offs[node];
    const int cnt = offs[node + 1] - beg;
    const float sd = s_dst[node];

    float a[8] = {0.f,0.f,0.f,0.f,0.f,0.f,0.f,0.f};
    float bacc[8] = {0.f,0.f,0.f,0.f,0.f,0.f,0.f,0.f};

    auto fma8 = [&](float* ac, float w, const uint4& v) {
        ac[0] = fmaf(w, BF_LO(v.x), ac[0]); ac[1] = fmaf(w, BF_HI(v.x), ac[1]);
        ac[2] = fmaf(w, BF_LO(v.y), ac[2]); ac[3] = fmaf(w, BF_HI(v.y), ac[3]);
        ac[4] = fmaf(w, BF_LO(v.z), ac[4]); ac[5] = fmaf(w, BF_HI(v.z), ac[5]);
        ac[6] = fmaf(w, BF_LO(v.w), ac[6]); ac[7] = fmaf(w, BF_HI(v.w), ac[7]);
    };

    if (cnt <= 64) {
        int s = 0; float e = -INFINITY;
        if (lane < cnt) {
            s = adj[beg + lane];
            float t = s_src[s] + sd;
            e = (t >= 0.f) ? t : NEG_SLOPE * t;
        }
        float mx = e;
#pragma unroll
        for (int o = 32; o; o >>= 1) mx = fmaxf(mx, __shfl_xor(mx, o, 64));
        float ex = (lane < cnt) ? __expf(e - mx) : 0.f;
        float sum = ex;
#pragma unroll
        for (int o = 32; o; o >>= 1) sum += __shfl_xor(sum, o, 64);
        const float inv = (cnt > 0) ? 1.f / sum : 0.f;
        const float w = ex * inv;       // 0 for lanes >= cnt

        for (int jj = 0; jj < cnt; jj += 8) {
            const int ja = jj + q;             // <= 59
            const int jb = ja + 4;             // <= 63
            float wa = __shfl(w, ja, 64); int sa = __shfl(s, ja, 64);
            float wb = __shfl(w, jb, 64); int sb = __shfl(s, jb, 64);
            wa = (ja < cnt) ? wa : 0.f;        // value predication, exec-safe
            wb = (jb < cnt) ? wb : 0.f;
            uint4 za = *(const uint4*)&z[(size_t)sa * D + l16 * 8];
            uint4 zb = *(const uint4*)&z[(size_t)sb * D + l16 * 8];
            fma8(a, wa, za);
            fma8(bacc, wb, zb);
        }
    } else {
        // rare general path (cnt > 64): 3-pass chunked, same shfl rule
        float mx = -INFINITY;
        for (int j = lane; j < cnt; j += 64) {
            float t = s_src[adj[beg + j]] + sd;
            t = (t >= 0.f) ? t : NEG_SLOPE * t;
            mx = fmaxf(mx, t);
        }
#pragma unroll
        for (int o = 32; o; o >>= 1) mx = fmaxf(mx, __shfl_xor(mx, o, 64));
        float sum = 0.f;
        for (int j = lane; j < cnt; j += 64) {
            float t = s_src[adj[beg + j]] + sd;
            t = (t >= 0.f) ? t : NEG_SLOPE * t;
            sum += __expf(t - mx);
        }
#pragma unroll
        for (int o = 32; o; o >>= 1) sum += __shfl_xor(sum, o, 64);
        const float inv = 1.f / sum;
        for (int base2 = 0; base2 < cnt; base2 += 64) {
            const int cc = min(64, cnt - base2);
            int s = 0; float w = 0.f;
            if (lane < cc) {
                s = adj[beg + base2 + lane];
                float t = s_src[s] + sd;
                t = (t >= 0.f) ? t : NEG_SLOPE * t;
                w = __expf(t - mx) * inv;
            }
            for (int jj = 0; jj < cc; jj += 8) {
                const int ja = jj + q;
                const int jb = ja + 4;
                float wa = __shfl(w, ja, 64); int sa = __shfl(s, ja, 64);
                float wb = __shfl(w, jb, 64); int sb = __shfl(s, jb, 64);
                wa = (ja < cc) ? wa : 0.f;
                wb = (jb < cc) ? wb : 0.f;
                uint4 za = *(const uint4*)&z[(size_t)sa * D + l16 * 8];
                uint4 zb = *(const uint4*)&z[(size_t)sb * D + l16 * 8];
                fma8(a, wa, za);
                fma8(bacc, wb, zb);
            }
        }
    }

    // merge unroll streams, then quads (xor-16, xor-32; full exec)
#pragma unroll
    for (int i = 0; i < 8; ++i) {
        a[i] += bacc[i];
        a[i] += __shfl_xor(a[i], 16, 64);
        a[i] += __shfl_xor(a[i], 32, 64);
    }
    if (q == 0) {
        float* o = &out[(size_t)node * D + l16 * 8];
        *(float4*)o       = make_float4(a[0], a[1], a[2], a[3]);
        *(float4*)(o + 4) = make_float4(a[4], a[5], a[6], a[7]);
    }
}

// ---------------- launch ----------------
extern "C" void kernel_launch(void* const* d_in, const int* in_sizes, int n_in,
                              void* d_out, int out_size, void* d_ws, size_t ws_size,
                              hipStream_t stream) {
    const float* h    = (const float*)d_in[0];
    const float* W    = (const float*)d_in[1];
    const float* aw   = (const float*)d_in[2];
    const int*   esrc = (const int*)d_in[3];
    const int*   edst = (const int*)d_in[4];
    float* out = (float*)d_out;

    const int N = in_sizes[0] / D;     // 100000
    const int E = in_sizes[3];         // 1600000
    const int NB1 = (N + 127) >> BSHIFT;

    char* p = (char*)d_ws;
    auto carve = [&](size_t bytes) {
        void* r = (void*)p;
        p += (bytes + 255) & ~size_t(255);
        return r;
    };
    unsigned short* z = (unsigned short*)carve(size_t(N) * D * sizeof(unsigned short));
    float* s_src  = (float*)carve(size_t(N) * sizeof(float));
    float* s_dst  = (float*)carve(size_t(N) * sizeof(float));
    int*   offs   = (int*)carve(size_t(N + 1) * sizeof(int));
    int*   adj    = (int*)carve(size_t(E) * sizeof(int));
    int*   pairs  = (int*)carve(size_t(E) * sizeof(int));
    int*   ccnt   = (int*)carve(size_t(B1 * NG) * sizeof(int));
    int*   gs     = (int*)carve(size_t(B1 * NG) * sizeof(int));
    int*   gcur   = (int*)carve(size_t(B1 * NG) * sizeof(int));
    int*   bstart = (int*)carve(size_t(B1) * sizeof(int));
    (void)ws_size; (void)n_in; (void)out_size;

    zero_i32<<<(B1 * NG + 255) / 256, 256, 0, stream>>>(ccnt, B1 * NG);
    gemm_zs<<<(N + 31) / 32, 256, 0, stream>>>(h, W, aw, z, s_src, s_dst, N);
    coarse_count<<<(E + 255) / 256, 256, 0, stream>>>(edst, ccnt, E);
    bucket_scan<<<1, B1, 0, stream>>>(ccnt, gs, gcur, bstart, offs, E, N);
    coarse_scatter<<<(E + 255) / 256, 256, 0, stream>>>(esrc, edst, gcur, pairs, E);
    fine_build<<<NB1, 256, 0, stream>>>(pairs, gs, gcur, bstart, offs, adj, N);
    aggregate<<<(N + 3) / 4, 256, 0, stream>>>(z, s_src, s_dst, offs, adj, out, N);
}

// Round 6
// 379.013 us; speedup vs baseline: 1.3647x; 1.1315x over previous
//
#include <hip/hip_runtime.h>

#define D 128            // D_IN == D_OUT == 128
#define NEG_SLOPE 0.01f
#define BSHIFT 7         // 128 dst values per coarse bucket
#define B1 1024          // max coarse buckets (N <= 131072)
#define NG 8             // writer groups (~XCDs) per bucket
#define STR 136          // LDS W stride in bf16 elems (pad 8 -> 2-way alias, free)

typedef __attribute__((ext_vector_type(8))) short short8;
typedef __attribute__((ext_vector_type(4))) float floatx4;

// bf16 helpers
__device__ __forceinline__ unsigned f2bf_rne(float x) {
    unsigned u = __float_as_uint(x);
    return (u + 0x7fffu + ((u >> 16) & 1u)) >> 16;
}
#define BF_LO(u) __uint_as_float((u) << 16)
#define BF_HI(u) __uint_as_float((u) & 0xffff0000u)

// ---------------- utility ----------------
__global__ void zero_i32(int* __restrict__ p, int n) {
    int i = blockIdx.x * blockDim.x + threadIdx.x;
    if (i < n) p[i] = 0;
}

// ---- z = h @ W via SPLIT-bf16 MFMA (fp32-accurate: hi*hi + lo*hi + hi*lo;
// dropped lo*lo ~2^-18). Wave = 16 rows x 128 cols, 8 C-frags. W staged once
// per block in LDS, transposed + hi/lo split. Scores fused from C-frags.
// Fragment maps (doc-verified): A[m=lane&15][k=quad*8+j]; B[k=quad*8+j][n=lane&15];
// C/D col=lane&15, row=quad*4+reg.
__global__ __launch_bounds__(256) void gemm_zs(const float* __restrict__ h,
                                               const float* __restrict__ W,
                                               const float* __restrict__ aw,
                                               unsigned short* __restrict__ z,
                                               float* __restrict__ s_src,
                                               float* __restrict__ s_dst, int N) {
    __shared__ unsigned short ws_hi[D * STR];   // 34 KB
    __shared__ unsigned short ws_lo[D * STR];   // 34 KB
    const int t = threadIdx.x;
    // stage W: read [k][n] coalesced, store transposed [n][k] hi/lo
    for (int i = t; i < D * D; i += 256) {
        int k = i >> 7, n = i & 127;
        float x = W[i];
        unsigned hi = f2bf_rne(x);
        float hf = __uint_as_float(hi << 16);
        unsigned lo = __float_as_uint(x - hf) >> 16;
        ws_hi[n * STR + k] = (unsigned short)hi;
        ws_lo[n * STR + k] = (unsigned short)lo;
    }
    __syncthreads();

    const int lane = t & 63, quad = lane >> 4, l16 = lane & 15;
    const int rowbase = blockIdx.x * 64 + (t >> 6) * 16;
    const int arow = min(rowbase + l16, N - 1);          // clamp: unused C rows unsaved
    const float* __restrict__ hrow = h + (size_t)arow * D;

    floatx4 acc[8];
#pragma unroll
    for (int ct = 0; ct < 8; ++ct) acc[ct] = (floatx4){0.f, 0.f, 0.f, 0.f};

#pragma unroll
    for (int kk = 0; kk < 4; ++kk) {
        const int k0 = kk * 32 + quad * 8;
        float4 x0 = *(const float4*)&hrow[k0];
        float4 x1 = *(const float4*)&hrow[k0 + 4];
        float xs[8] = {x0.x, x0.y, x0.z, x0.w, x1.x, x1.y, x1.z, x1.w};
        union { short8 v; unsigned short u[8]; } ahi, alo;
#pragma unroll
        for (int i = 0; i < 8; ++i) {
            unsigned hi = f2bf_rne(xs[i]);
            float hf = __uint_as_float(hi << 16);
            ahi.u[i] = (unsigned short)hi;
            alo.u[i] = (unsigned short)(__float_as_uint(xs[i] - hf) >> 16);
        }
#pragma unroll
        for (int ct = 0; ct < 8; ++ct) {
            const int bo = (ct * 16 + l16) * STR + k0;   // 16B-aligned
            short8 bhi = *(const short8*)&ws_hi[bo];
            short8 blo = *(const short8*)&ws_lo[bo];
            acc[ct] = __builtin_amdgcn_mfma_f32_16x16x32_bf16(ahi.v, bhi, acc[ct], 0, 0, 0);
            acc[ct] = __builtin_amdgcn_mfma_f32_16x16x32_bf16(alo.v, bhi, acc[ct], 0, 0, 0);
            acc[ct] = __builtin_amdgcn_mfma_f32_16x16x32_bf16(ahi.v, blo, acc[ct], 0, 0, 0);
        }
    }

    // z store (bf16) from C-frags: elem (row=quad*4+reg, col=ct*16+l16)
#pragma unroll
    for (int ct = 0; ct < 8; ++ct)
#pragma unroll
        for (int reg = 0; reg < 4; ++reg) {
            int r = rowbase + quad * 4 + reg;
            if (r < N)
                z[(size_t)r * D + ct * 16 + l16] = (unsigned short)f2bf_rne(acc[ct][reg]);
        }

    // fused scores: per-lane partials for this lane's 4 rows, reduce across l16
    float ps[4] = {0.f, 0.f, 0.f, 0.f}, pd[4] = {0.f, 0.f, 0.f, 0.f};
#pragma unroll
    for (int ct = 0; ct < 8; ++ct) {
        float as = aw[ct * 16 + l16];
        float ad = aw[128 + ct * 16 + l16];
#pragma unroll
        for (int reg = 0; reg < 4; ++reg) {
            ps[reg] = fmaf(acc[ct][reg], as, ps[reg]);
            pd[reg] = fmaf(acc[ct][reg], ad, pd[reg]);
        }
    }
#pragma unroll
    for (int reg = 0; reg < 4; ++reg)
#pragma unroll
        for (int o = 1; o < 16; o <<= 1) {               // all 64 lanes active
            ps[reg] += __shfl_xor(ps[reg], o, 64);
            pd[reg] += __shfl_xor(pd[reg], o, 64);
        }
    if (l16 == 0) {
#pragma unroll
        for (int reg = 0; reg < 4; ++reg) {
            int r = rowbase + quad * 4 + reg;
            if (r < N) { s_src[r] = ps[reg]; s_dst[r] = pd[reg]; }
        }
    }
}

// ---------------- CSR build: two-level counting sort ----------------
__global__ __launch_bounds__(256) void coarse_count(const int* __restrict__ edst,
                                                    int* __restrict__ ccnt, int E) {
    int e = blockIdx.x * 256 + threadIdx.x;
    if (e < E) {
        int bkt = edst[e] >> BSHIFT;
        atomicAdd(&ccnt[bkt * NG + (blockIdx.x & (NG - 1))], 1);
    }
}

__global__ __launch_bounds__(1024) void bucket_scan(const int* __restrict__ ccnt,
                                                    int* __restrict__ gs,
                                                    int* __restrict__ gcur,
                                                    int* __restrict__ bstart,
                                                    int* __restrict__ offs,
                                                    int E, int N) {
    __shared__ int sm[B1];
    const int t = threadIdx.x;
    int c[NG]; int tot = 0;
#pragma unroll
    for (int g = 0; g < NG; ++g) { c[g] = ccnt[t * NG + g]; tot += c[g]; }
    sm[t] = tot;
    __syncthreads();
    for (int off = 1; off < B1; off <<= 1) {
        int v = (t >= off) ? sm[t - off] : 0;
        __syncthreads();
        sm[t] += v;
        __syncthreads();
    }
    int excl = sm[t] - tot;
    bstart[t] = excl;
    int run = excl;
#pragma unroll
    for (int g = 0; g < NG; ++g) {
        gs[t * NG + g] = run;
        gcur[t * NG + g] = run;
        run += c[g];
    }
    if (t == 0) offs[N] = E;
}

// scatter packed (src<<7 | dst&127); valid since N <= 2^17 (17+7=24 bits)
__global__ __launch_bounds__(256) void coarse_scatter(const int* __restrict__ esrc,
                                                      const int* __restrict__ edst,
                                                      int* __restrict__ gcur,
                                                      int* __restrict__ pairs, int E) {
    int e = blockIdx.x * 256 + threadIdx.x;
    if (e < E) {
        int d = edst[e];
        int bkt = d >> BSHIFT;
        int pos = atomicAdd(&gcur[bkt * NG + (blockIdx.x & (NG - 1))], 1);
        pairs[pos] = (esrc[e] << BSHIFT) | (d & 127);
    }
}

// one block per bucket: LDS histogram+scan over 128 dsts -> offs + adj.
__global__ __launch_bounds__(256) void fine_build(const int* __restrict__ pairs,
                                                  const int* __restrict__ gs,
                                                  const int* __restrict__ gcur,
                                                  const int* __restrict__ bstart,
                                                  int* __restrict__ offs,
                                                  int* __restrict__ adj, int N) {
    __shared__ int cnt[128], sc[128], cur[128];
    const int b = blockIdx.x;
    const int base = b << BSHIFT;
    const int nd = min(128, N - base);
    const int t = threadIdx.x;
    if (t < 128) { cnt[t] = 0; cur[t] = 0; }
    __syncthreads();
#pragma unroll
    for (int g = 0; g < NG; ++g) {
        const int s0 = gs[b * NG + g], e0 = gcur[b * NG + g];
        for (int i = s0 + t; i < e0; i += 256)
            atomicAdd(&cnt[pairs[i] & 127], 1);
    }
    __syncthreads();
    if (t < 128) sc[t] = cnt[t];
    __syncthreads();
    for (int off = 1; off < 128; off <<= 1) {
        int v = (t < 128 && t >= off) ? sc[t - off] : 0;
        __syncthreads();
        if (t < 128) sc[t] += v;
        __syncthreads();
    }
    const int bs = bstart[b];
    if (t < nd) offs[base + t] = bs + sc[t] - cnt[t];     // exclusive
    __syncthreads();
#pragma unroll
    for (int g = 0; g < NG; ++g) {
        const int s0 = gs[b * NG + g], e0 = gcur[b * NG + g];
        for (int i = s0 + t; i < e0; i += 256) {
            int pk = pairs[i];
            int d = pk & 127;
            int pos = bs + (sc[d] - cnt[d]) + atomicAdd(&cur[d], 1);
            adj[pos] = pk >> BSHIFT;
        }
    }
}

// ---------------- per-dst-node softmax + weighted sum: one wave per node ------
// z rows bf16 (256B): each 16-lane QUAD covers one row (16B/lane uint4),
// 4 edges/iter x2 unroll. Every __shfl executes with ALL 64 lanes active;
// validity via value predication of the shfl'd weight.
__global__ __launch_bounds__(256) void aggregate(const unsigned short* __restrict__ z,
                                                 const float* __restrict__ s_src,
                                                 const float* __restrict__ s_dst,
                                                 const int* __restrict__ offs,
                                                 const int* __restrict__ adj,
                                                 float* __restrict__ out, int N) {
    const int lane = threadIdx.x & 63;
    const int q    = lane >> 4;
    const int l16  = lane & 15;
    const int node = blockIdx.x * 4 + (threadIdx.x >> 6);
    if (node >= N) return;
    const int beg = offs[node];
    const int cnt = offs[node + 1] - beg;
    const float sd = s_dst[node];

    float a[8] = {0.f,0.f,0.f,0.f,0.f,0.f,0.f,0.f};
    float bacc[8] = {0.f,0.f,0.f,0.f,0.f,0.f,0.f,0.f};

    auto fma8 = [&](float* ac, float w, const uint4& v) {
        ac[0] = fmaf(w, BF_LO(v.x), ac[0]); ac[1] = fmaf(w, BF_HI(v.x), ac[1]);
        ac[2] = fmaf(w, BF_LO(v.y), ac[2]); ac[3] = fmaf(w, BF_HI(v.y), ac[3]);
        ac[4] = fmaf(w, BF_LO(v.z), ac[4]); ac[5] = fmaf(w, BF_HI(v.z), ac[5]);
        ac[6] = fmaf(w, BF_LO(v.w), ac[6]); ac[7] = fmaf(w, BF_HI(v.w), ac[7]);
    };

    if (cnt <= 64) {
        int s = 0; float e = -INFINITY;
        if (lane < cnt) {
            s = adj[beg + lane];
            float t = s_src[s] + sd;
            e = (t >= 0.f) ? t : NEG_SLOPE * t;
        }
        float mx = e;
#pragma unroll
        for (int o = 32; o; o >>= 1) mx = fmaxf(mx, __shfl_xor(mx, o, 64));
        float ex = (lane < cnt) ? __expf(e - mx) : 0.f;
        float sum = ex;
#pragma unroll
        for (int o = 32; o; o >>= 1) sum += __shfl_xor(sum, o, 64);
        const float inv = (cnt > 0) ? 1.f / sum : 0.f;
        const float w = ex * inv;

        for (int jj = 0; jj < cnt; jj += 8) {
            const int ja = jj + q;
            const int jb = ja + 4;
            float wa = __shfl(w, ja, 64); int sa = __shfl(s, ja, 64);
            float wb = __shfl(w, jb, 64); int sb = __shfl(s, jb, 64);
            wa = (ja < cnt) ? wa : 0.f;
            wb = (jb < cnt) ? wb : 0.f;
            uint4 za = *(const uint4*)&z[(size_t)sa * D + l16 * 8];
            uint4 zb = *(const uint4*)&z[(size_t)sb * D + l16 * 8];
            fma8(a, wa, za);
            fma8(bacc, wb, zb);
        }
    } else {
        float mx = -INFINITY;
        for (int j = lane; j < cnt; j += 64) {
            float t = s_src[adj[beg + j]] + sd;
            t = (t >= 0.f) ? t : NEG_SLOPE * t;
            mx = fmaxf(mx, t);
        }
#pragma unroll
        for (int o = 32; o; o >>= 1) mx = fmaxf(mx, __shfl_xor(mx, o, 64));
        float sum = 0.f;
        for (int j = lane; j < cnt; j += 64) {
            float t = s_src[adj[beg + j]] + sd;
            t = (t >= 0.f) ? t : NEG_SLOPE * t;
            sum += __expf(t - mx);
        }
#pragma unroll
        for (int o = 32; o; o >>= 1) sum += __shfl_xor(sum, o, 64);
        const float inv = 1.f / sum;
        for (int base2 = 0; base2 < cnt; base2 += 64) {
            const int cc = min(64, cnt - base2);
            int s = 0; float w = 0.f;
            if (lane < cc) {
                s = adj[beg + base2 + lane];
                float t = s_src[s] + sd;
                t = (t >= 0.f) ? t : NEG_SLOPE * t;
                w = __expf(t - mx) * inv;
            }
            for (int jj = 0; jj < cc; jj += 8) {
                const int ja = jj + q;
                const int jb = ja + 4;
                float wa = __shfl(w, ja, 64); int sa = __shfl(s, ja, 64);
                float wb = __shfl(w, jb, 64); int sb = __shfl(s, jb, 64);
                wa = (ja < cc) ? wa : 0.f;
                wb = (jb < cc) ? wb : 0.f;
                uint4 za = *(const uint4*)&z[(size_t)sa * D + l16 * 8];
                uint4 zb = *(const uint4*)&z[(size_t)sb * D + l16 * 8];
                fma8(a, wa, za);
                fma8(bacc, wb, zb);
            }
        }
    }

#pragma unroll
    for (int i = 0; i < 8; ++i) {
        a[i] += bacc[i];
        a[i] += __shfl_xor(a[i], 16, 64);
        a[i] += __shfl_xor(a[i], 32, 64);
    }
    if (q == 0) {
        float* o = &out[(size_t)node * D + l16 * 8];
        *(float4*)o       = make_float4(a[0], a[1], a[2], a[3]);
        *(float4*)(o + 4) = make_float4(a[4], a[5], a[6], a[7]);
    }
}

// ---------------- launch ----------------
extern "C" void kernel_launch(void* const* d_in, const int* in_sizes, int n_in,
                              void* d_out, int out_size, void* d_ws, size_t ws_size,
                              hipStream_t stream) {
    const float* h    = (const float*)d_in[0];
    const float* W    = (const float*)d_in[1];
    const float* aw   = (const float*)d_in[2];
    const int*   esrc = (const int*)d_in[3];
    const int*   edst = (const int*)d_in[4];
    float* out = (float*)d_out;

    const int N = in_sizes[0] / D;     // 100000
    const int E = in_sizes[3];         // 1600000
    const int NB1 = (N + 127) >> BSHIFT;

    char* p = (char*)d_ws;
    auto carve = [&](size_t bytes) {
        void* r = (void*)p;
        p += (bytes + 255) & ~size_t(255);
        return r;
    };
    unsigned short* z = (unsigned short*)carve(size_t(N) * D * sizeof(unsigned short));
    float* s_src  = (float*)carve(size_t(N) * sizeof(float));
    float* s_dst  = (float*)carve(size_t(N) * sizeof(float));
    int*   offs   = (int*)carve(size_t(N + 1) * sizeof(int));
    int*   adj    = (int*)carve(size_t(E) * sizeof(int));
    int*   pairs  = (int*)carve(size_t(E) * sizeof(int));
    int*   ccnt   = (int*)carve(size_t(B1 * NG) * sizeof(int));
    int*   gs     = (int*)carve(size_t(B1 * NG) * sizeof(int));
    int*   gcur   = (int*)carve(size_t(B1 * NG) * sizeof(int));
    int*   bstart = (int*)carve(size_t(B1) * sizeof(int));
    (void)ws_size; (void)n_in; (void)out_size;

    zero_i32<<<(B1 * NG + 255) / 256, 256, 0, stream>>>(ccnt, B1 * NG);
    gemm_zs<<<(N + 63) / 64, 256, 0, stream>>>(h, W, aw, z, s_src, s_dst, N);
    coarse_count<<<(E + 255) / 256, 256, 0, stream>>>(edst, ccnt, E);
    bucket_scan<<<1, B1, 0, stream>>>(ccnt, gs, gcur, bstart, offs, E, N);
    coarse_scatter<<<(E + 255) / 256, 256, 0, stream>>>(esrc, edst, gcur, pairs, E);
    fine_build<<<NB1, 256, 0, stream>>>(pairs, gs, gcur, bstart, offs, adj, N);
    aggregate<<<(N + 3) / 4, 256, 0, stream>>>(z, s_src, s_dst, offs, adj, out, N);
}